// Round 2
// 428.440 us; speedup vs baseline: 1.0215x; 1.0215x over previous
//
#include <hip/hip_runtime.h>
#include <math.h>

#define NN 20000
typedef unsigned int uint;
typedef unsigned short ushort;
typedef __attribute__((ext_vector_type(8))) short bf16x8;
typedef __attribute__((ext_vector_type(4))) float f32x4;

union U8 { uint4 u; bf16x8 v; };

__device__ __forceinline__ ushort f2b(float x) {           // RNE
    uint u = __float_as_uint(x);
    return (ushort)((u + 0x7FFFu + ((u >> 16) & 1u)) >> 16);
}
__device__ __forceinline__ float b2f(ushort b) {
    return __uint_as_float(((uint)b) << 16);
}
// single-instruction pack: dst.lo = bf16_rne(lo), dst.hi = bf16_rne(hi)
__device__ __forceinline__ uint cvt_pk_bf16(float lo, float hi) {
    uint r;
    asm("v_cvt_pk_bf16_f32 %0, %1, %2" : "=v"(r) : "v"(lo), "v"(hi));
    return r;
}

// ---------- Prep: padded bf16 weights ----------
// WtT2[o][k'=i*64+j] (64 x 3200), zero at o>=50 / j>=50.  WpB[d][e] (64 x 384).
__global__ __launch_bounds__(256) void kPrep(const float* __restrict__ Wbil,
                                             const float* __restrict__ Wp,
                                             ushort* __restrict__ WtT2,
                                             ushort* __restrict__ WpB) {
    const int stride = gridDim.x * 256;
    for (int idx = blockIdx.x * 256 + threadIdx.x; idx < 64 * 3200; idx += stride) {
        int o = idx / 3200, k = idx - o * 3200;
        int i = k >> 6, j = k & 63;
        WtT2[idx] = (o < 50 && j < 50) ? f2b(Wbil[o * 2500 + i * 50 + j]) : (ushort)0;
    }
    for (int idx = blockIdx.x * 256 + threadIdx.x; idx < 64 * 384; idx += stride) {
        int d = idx / 384, e = idx - d * 384;
        WpB[idx] = (d < 50 && e < 300) ? f2b(Wp[d * 300 + e]) : (ushort)0;
    }
}

// ---------- Ent: ent[N,64] f32 = entity[N,384pad] @ WpB^T + bp (computed ONCE) ----------
__global__ __launch_bounds__(256) void kEnt(const float* __restrict__ entity,
                                            const float* __restrict__ bp,
                                            const ushort* __restrict__ WpB,
                                            float* __restrict__ entG) {
    __shared__ ushort BsE[64 * 144];
    __shared__ ushort BsW[64 * 144];
    const int tid = threadIdx.x;
    const int n0 = blockIdx.x * 64;
    const int w = tid >> 6, lane = tid & 63;
    const int c = lane & 15, quad = lane >> 4;
    const int nl = tid >> 2;              // staging row 0..63
    const int kc = (tid & 3) * 32;        // staging col chunk (ushorts)
    const int myrow = w * 16 + c;

    f32x4 accE[4] = {{0.f,0.f,0.f,0.f},{0.f,0.f,0.f,0.f},{0.f,0.f,0.f,0.f},{0.f,0.f,0.f,0.f}};
    for (int t = 0; t < 3; ++t) {
        const int e0 = t * 128;
        __syncthreads();
        {   // stage entity -> BsE (bf16 via v_cvt_pk)
            const int node = n0 + nl;
            uint pk[16];
            #pragma unroll
            for (int u8 = 0; u8 < 8; ++u8) {
                const int e = e0 + kc + u8 * 4;
                float4 v = make_float4(0.f, 0.f, 0.f, 0.f);
                if (node < NN && e < 300)
                    v = *(const float4*)(entity + (size_t)node * 300 + e);
                pk[u8 * 2]     = cvt_pk_bf16(v.x, v.y);
                pk[u8 * 2 + 1] = cvt_pk_bf16(v.z, v.w);
            }
            uint4* dst = (uint4*)(BsE + nl * 144 + kc);
            #pragma unroll
            for (int m = 0; m < 4; ++m)
                dst[m] = make_uint4(pk[m*4], pk[m*4+1], pk[m*4+2], pk[m*4+3]);
        }
        {   // stage WpB -> BsW
            const uint4* src = (const uint4*)(WpB + nl * 384 + e0 + kc);
            uint4 v0 = src[0], v1 = src[1], v2 = src[2], v3 = src[3];
            uint4* dst = (uint4*)(BsW + nl * 144 + kc);
            dst[0] = v0; dst[1] = v1; dst[2] = v2; dst[3] = v3;
        }
        __syncthreads();
        #pragma unroll
        for (int ks = 0; ks < 4; ++ks) {
            bf16x8 a = *(const bf16x8*)(BsE + myrow * 144 + ks * 32 + quad * 8);
            #pragma unroll
            for (int nt = 0; nt < 4; ++nt) {
                bf16x8 b = *(const bf16x8*)(BsW + (nt * 16 + c) * 144 + ks * 32 + quad * 8);
                accE[nt] = __builtin_amdgcn_mfma_f32_16x16x32_bf16(a, b, accE[nt], 0, 0, 0);
            }
        }
    }
    // epilogue: f32 ent, full 64-wide rows (zeros at o>=50 so bilinear A-products are clean)
    #pragma unroll
    for (int nt = 0; nt < 4; ++nt) {
        const int o = nt * 16 + c;
        const float bias = (o < 50) ? bp[o] : 0.f;
        #pragma unroll
        for (int r = 0; r < 4; ++r) {
            const int node = n0 + w * 16 + quad * 4 + r;
            if (node < NN)
                entG[(size_t)node * 64 + o] = (o < 50) ? (accE[nt][r] + bias) : 0.f;
        }
    }
}

// ---------- Main: bilinear GEMM over k' = i*64+j, A-products packed via cvt_pk ----------
// 64 nodes/block, split-K=2 (h=0: i<26 -> 13 tiles; h=1: i in [26,50) -> 12 tiles).
__global__ __launch_bounds__(256, 3) void kMain(
    const float* __restrict__ q,       // [N,50]
    const float* __restrict__ entG,    // [N,64] f32 (from kEnt)
    const ushort* __restrict__ WtT2,   // [64][3200] bf16
    float* __restrict__ part)          // [2][NN][64]
{
    __shared__ ushort qs[64 * 50];        // bf16 q tile [node][i]
    __shared__ ushort Bs[2][64 * 144];    // B tiles [row][k], stride 144 (288 B)

    const int tid = threadIdx.x;
    const int h = blockIdx.x & 1;
    const int n0 = (blockIdx.x >> 1) * 64;
    const int w = tid >> 6, lane = tid & 63;
    const int c = lane & 15, quad = lane >> 4;
    const int nl = tid >> 2;              // staging row 0..63
    const int kc = (tid & 3) * 32;        // staging col chunk (ushorts)
    const int myrow = w * 16 + c;         // this lane's node row (0..63)

    // stage q tile as bf16
    for (int i = tid; i < 3200; i += 256) {
        int r = i / 50, d = i - r * 50;
        float v = (n0 + r < NN) ? q[(size_t)(n0 + r) * 50 + d] : 0.f;
        qs[i] = f2b(v);
    }

    // this lane's ent slices in f32 registers (j = quad*8.. and 32+quad*8..)
    const int mynode = n0 + myrow;
    float ef[16];
    {
        float4 a0 = make_float4(0.f,0.f,0.f,0.f), a1 = a0, b0 = a0, b1 = a0;
        if (mynode < NN) {
            const float4* ep = (const float4*)(entG + (size_t)mynode * 64 + quad * 8);
            a0 = ep[0]; a1 = ep[1];
            b0 = ep[8]; b1 = ep[9];      // +32 floats
        }
        ef[0]=a0.x;  ef[1]=a0.y;  ef[2]=a0.z;  ef[3]=a0.w;
        ef[4]=a1.x;  ef[5]=a1.y;  ef[6]=a1.z;  ef[7]=a1.w;
        ef[8]=b0.x;  ef[9]=b0.y;  ef[10]=b0.z; ef[11]=b0.w;
        ef[12]=b1.x; ef[13]=b1.y; ef[14]=b1.z; ef[15]=b1.w;
    }
    const ushort* qrow = qs + myrow * 50;

    const int kb0 = h ? 1664 : 0;
    const int ntiles = h ? 12 : 13;
    f32x4 acc[4] = {{0.f,0.f,0.f,0.f},{0.f,0.f,0.f,0.f},{0.f,0.f,0.f,0.f},{0.f,0.f,0.f,0.f}};

    {   // stage tile 0 -> Bs[0]
        const uint4* src = (const uint4*)(WtT2 + nl * 3200 + kb0 + kc);
        uint4 v0 = src[0], v1 = src[1], v2 = src[2], v3 = src[3];
        uint4* dst = (uint4*)(&Bs[0][0] + nl * 144 + kc);
        dst[0] = v0; dst[1] = v1; dst[2] = v2; dst[3] = v3;
    }
    __syncthreads();

    for (int t = 0; t < ntiles; ++t) {
        // prefetch next W tile into registers
        uint4 p0, p1, p2, p3;
        if (t + 1 < ntiles) {
            const uint4* src = (const uint4*)(WtT2 + nl * 3200 + kb0 + (t + 1) * 128 + kc);
            p0 = src[0]; p1 = src[1]; p2 = src[2]; p3 = src[3];
        }
        const ushort* Bcur = &Bs[t & 1][0];
        const int i0 = (kb0 >> 6) + 2 * t;
        #pragma unroll
        for (int ip = 0; ip < 2; ++ip) {
            const float qv = b2f(qrow[i0 + ip]);
            #pragma unroll
            for (int hf = 0; hf < 2; ++hf) {
                const float* e = ef + hf * 8;
                U8 ua;
                ua.u = make_uint4(cvt_pk_bf16(e[0] * qv, e[1] * qv),
                                  cvt_pk_bf16(e[2] * qv, e[3] * qv),
                                  cvt_pk_bf16(e[4] * qv, e[5] * qv),
                                  cvt_pk_bf16(e[6] * qv, e[7] * qv));
                const int ko = ip * 64 + hf * 32 + quad * 8;
                #pragma unroll
                for (int nt = 0; nt < 4; ++nt) {
                    bf16x8 b = *(const bf16x8*)(Bcur + (nt * 16 + c) * 144 + ko);
                    acc[nt] = __builtin_amdgcn_mfma_f32_16x16x32_bf16(ua.v, b, acc[nt], 0, 0, 0);
                }
            }
        }
        if (t + 1 < ntiles) {
            uint4* dst = (uint4*)(&Bs[(t + 1) & 1][0] + nl * 144 + kc);
            dst[0] = p0; dst[1] = p1; dst[2] = p2; dst[3] = p3;
        }
        __syncthreads();
    }

    // epilogue: part[h][node][o]
    #pragma unroll
    for (int nt = 0; nt < 4; ++nt) {
        const int o = nt * 16 + c;
        #pragma unroll
        for (int r = 0; r < 4; ++r) {
            const int node = n0 + w * 16 + quad * 4 + r;
            if (node < NN)
                part[((size_t)h * NN + node) * 64 + o] = acc[nt][r];
        }
    }
}

// ---------- B: weighted neighbor sum + Wg matvec + ELU + rank head ----------
// 8 nodes/block, 2 nodes per wave (50/64 lanes streaming).
__global__ __launch_bounds__(256) void kB(const float* __restrict__ nb,
                                          const float* __restrict__ scores,
                                          const float* __restrict__ part,
                                          const float* __restrict__ bbil,
                                          const float* __restrict__ Wg,
                                          const float* __restrict__ g_bias,
                                          const float* __restrict__ Wr,
                                          const float* __restrict__ br,
                                          float* __restrict__ out) {
    __shared__ float Wgs[50 * 51];
    __shared__ float scs[512];
    __shared__ float tv[8][52];
    __shared__ float cb[8][64];

    const int tid = threadIdx.x;
    const int n0 = blockIdx.x * 8;        // NN = 2500 * 8, no node guards needed

    for (int idx = tid; idx < 2500; idx += 256) {
        int o = idx / 50, d = idx - o * 50;
        Wgs[o * 51 + d] = Wg[idx];
    }
    scs[tid]       = scores[(size_t)n0 * 64 + tid];
    scs[tid + 256] = scores[(size_t)n0 * 64 + 256 + tid];
    ((float*)cb)[tid] = 0.f;
    ((float*)cb)[tid + 256] = 0.f;
    __syncthreads();

    const int w = tid >> 6, lane = tid & 63;
    const int half = lane >> 5, l = lane & 31;
    const int ni = 2 * w + half;          // node index within block, 0..7
    const int n = n0 + ni;
    if (l < 25) {
        const int d2 = l * 2;
        const float* base = nb + (size_t)n * 3150 + d2;
        const float* sw = &scs[ni * 64];
        float t0 = 0.f, t1 = 0.f;
        #pragma unroll 9
        for (int k = 0; k < 63; ++k) {
            const float2 v = *(const float2*)(base + k * 50);
            t0 += sw[k] * v.x; t1 += sw[k] * v.y;
        }
        const float2 p0 = *(const float2*)(part + (size_t)n * 64 + d2);
        const float2 p1 = *(const float2*)(part + ((size_t)NN + n) * 64 + d2);
        tv[ni][d2]     = t0 + sw[63] * (p0.x + p1.x + bbil[d2]);
        tv[ni][d2 + 1] = t1 + sw[63] * (p0.y + p1.y + bbil[d2 + 1]);
    }
    __syncthreads();

    // matvec + ELU + per-(n,o) head contribution: 400 tasks over 256 threads
    for (int p = tid; p < 400; p += 256) {
        const int n2 = p / 50, o = p - n2 * 50;
        const float* wrow = &Wgs[o * 51];
        const float* twv = &tv[n2][0];
        float a = g_bias[o];
        #pragma unroll 10
        for (int d = 0; d < 50; ++d) a += wrow[d] * twv[d];
        const float f = a > 0.f ? a : (__expf(a) - 1.f);
        cb[n2][o] = f * Wr[o];
    }
    __syncthreads();

    // reduce: one half-wave per node (cb rows padded with zeros at o>=50)
    float v = cb[ni][l] + cb[ni][l + 32];
    #pragma unroll
    for (int off = 16; off; off >>= 1) v += __shfl_xor(v, off);
    if (l == 0) out[n] = v + br[0];
}

extern "C" void kernel_launch(void* const* d_in, const int* in_sizes, int n_in,
                              void* d_out, int out_size, void* d_ws, size_t ws_size,
                              hipStream_t stream) {
    const float* q_   = (const float*)d_in[0];
    const float* ent  = (const float*)d_in[1];
    const float* nb   = (const float*)d_in[2];
    const float* scr  = (const float*)d_in[3];
    const float* Wp   = (const float*)d_in[4];
    const float* bp   = (const float*)d_in[5];
    const float* Wb   = (const float*)d_in[6];
    const float* bb   = (const float*)d_in[7];
    const float* Wg   = (const float*)d_in[8];
    const float* gb   = (const float*)d_in[9];
    const float* Wr   = (const float*)d_in[10];
    const float* br   = (const float*)d_in[11];
    float* out = (float*)d_out;

    ushort* WtT2 = (ushort*)d_ws;                  // 64*3200 ushorts = 409600 B
    ushort* WpB  = WtT2 + 64 * 3200;               // 64*384 ushorts  =  49152 B
    float*  entG = (float*)(WpB + 64 * 384);       // byte off 458752 (16B aligned), NN*64 f32
    float*  part = entG + (size_t)NN * 64;         // byte off 5578752 (16B aligned), 2*NN*64 f32

    hipLaunchKernelGGL(kPrep, dim3(256),  dim3(256), 0, stream, Wb, Wp, WtT2, WpB);
    hipLaunchKernelGGL(kEnt,  dim3(313),  dim3(256), 0, stream, ent, bp, WpB, entG);
    hipLaunchKernelGGL(kMain, dim3(626),  dim3(256), 0, stream, q_, entG, WtT2, part);
    hipLaunchKernelGGL(kB,    dim3(2500), dim3(256), 0, stream, nb, scr, part, bb, Wg, gb, Wr, br, out);
}